// Round 11
// baseline (585.140 us; speedup 1.0000x reference)
//
#include <hip/hip_runtime.h>
#include <stdint.h>

#define T_SEQ 500
#define D_IN  32
#define BDIM  256
#define ROWS  8

using short8  = __attribute__((ext_vector_type(8))) short;     // 8 x 16-bit payload
using half8   = __attribute__((ext_vector_type(8))) _Float16;  // 8 fp16
using fp16x2  = __attribute__((ext_vector_type(2))) __fp16;    // cvt_pkrtz return type
using float4_ = __attribute__((ext_vector_type(4))) float;     // MFMA C/D frag

#define MFMAH(a,b,c) __builtin_amdgcn_mfma_f32_16x16x32_f16((a),(b),(c),0,0,0)

// ---------------- LDS: 272B frag blocks (16 rows x 16B + 16B pad) ----------------
#define BLK 272
#define ENC_H(buf,kt,g)  ((((buf)*2+(kt))*4+(g))*BLK)                   // blocks 0..15
#define DEC_H(buf,kt,g)  (16*BLK + ((((buf)*2+(kt))*4+(g))*BLK))        // blocks 16..31
#define LDS_BYTES (32*BLK)   // 8704 B

// ---------------- workspace (bytes) — identical to r9 (proven) ----------------
#define WS_ENC   0                                // [kt3][w4][nt4][hl2][lane64] x16B (fp16)
#define WS_DEC0  (WS_ENC  + 3*4*4*2*64*16)        // 98304  (fp16 hi/lo)
#define WS_COMB  (WS_DEC0 + 2*4*4*2*64*16)        // 163840 (fp16 hi/lo)
#define WS_OUT   (WS_COMB + 2*4*4*2*64*16)        // 229376 : [kt2][ot2][hl2][lane64] (fp16)
#define WS_BENC  (WS_OUT  + 2*2*2*64*16)          // 237568 : [w4][nt4][lane64] f32
#define WS_BDEC0 (WS_BENC  + 4*4*64*4)            // 241664
#define WS_BCOMB (WS_BDEC0 + 4*4*64*4)            // 245760
#define WS_BOUT  (WS_BCOMB + 4*4*64*4)            // 249856 : [ot2][lane64] f32

// gate scale folded into weights: i,f,o -> -log2(e); g -> +2*log2(e)
#define S_SIG  (-1.4426950408889634f)
#define S_TANH ( 2.8853900817779268f)

__device__ __forceinline__ void split_f16(float v, unsigned short &hi, unsigned short &lo) {
    _Float16 h = (_Float16)v;
    _Float16 l = (_Float16)(v - (float)h);
    union { _Float16 f; unsigned short u; } a, b;
    a.f = h; b.f = l; hi = a.u; lo = b.u;
}
__device__ __forceinline__ unsigned short f16_bits(float v) {
    union { _Float16 f; unsigned short u; } t; t.f = (_Float16)v; return t.u;
}
// LDS-only barrier (no vmcnt drain: out-stores and x-prefetch loads stay in flight)
__device__ __forceinline__ void lds_barrier() {
    asm volatile("s_waitcnt lgkmcnt(0)\n\ts_barrier" ::: "memory");
}
// fused-rcp LSTM pointwise (ip,fp,op pre-scaled by -log2e; gp by +2log2e)
__device__ __forceinline__ float lstm_h(float ip, float fp, float gp, float op, float &cc) {
    const float ei = __builtin_amdgcn_exp2f(ip);
    const float ef = __builtin_amdgcn_exp2f(fp);
    const float eg = __builtin_amdgcn_exp2f(gp);
    const float eo = __builtin_amdgcn_exp2f(op);
    const float pig = (eg - 1.0f) * __builtin_amdgcn_rcpf((1.0f + ei) * (1.0f + eg));
    const float fa  = __builtin_amdgcn_rcpf(1.0f + ef);
    cc = __builtin_fmaf(fa, cc, pig);
    const float ec = __builtin_amdgcn_exp2f(cc * -2.8853900817779268f);
    return (1.0f - ec) * __builtin_amdgcn_rcpf((1.0f + eo) * (1.0f + ec));
}

// ==================== prep kernel (identical to r9, proven) ====================
// col map: wave w (0..3), tile nt = GATE, col c -> unit = w*16 + c, weight row n = nt*64 + unit
// frag element j of lane (rg=lane>>4): k = kt*32 + rg*8 + j
__global__ void __launch_bounds__(512)
prep_kernel(const float* __restrict__ Wih_e, const float* __restrict__ Whh_e,
            const float* __restrict__ b_e,
            const float* __restrict__ Wih_d, const float* __restrict__ Whh_d,
            const float* __restrict__ b_d,
            const float* __restrict__ Wout, const float* __restrict__ bout,
            char* __restrict__ ws)
{
    const int tid  = blockIdx.x * blockDim.x + threadIdx.x;
    const int nthr = gridDim.x * blockDim.x;

    // encoder fragments (fp16 hi/lo): slots (kt3, w4, nt4, lane64)
    for (int s = tid; s < 3*4*4*64; s += nthr) {
        const int lane = s & 63, nt = (s >> 6) & 3, w = (s >> 8) & 3, kt = s >> 10;
        const int rg = lane >> 4;
        const int n = nt*64 + w*16 + (lane & 15);
        const float sc = (nt == 2) ? S_TANH : S_SIG;
        short8 hi8, lo8;
        #pragma unroll
        for (int j = 0; j < 8; ++j) {
            const int k = kt*32 + rg*8 + j;
            const float wv = sc * ((k < 32) ? Wih_e[n*D_IN + k] : Whh_e[n*64 + k - 32]);
            unsigned short h_, l_; split_f16(wv, h_, l_);
            hi8[j] = (short)h_; lo8[j] = (short)l_;
        }
        const size_t base = (size_t)(((((kt*4+w)*4+nt)*2+0)*64 + lane)) * 16;
        *(short8*)(ws + WS_ENC + base)           = hi8;
        *(short8*)(ws + WS_ENC + base + 64*16)   = lo8;
    }

    // decoder step-0 (Whh_d) and combined (Whh_d + Wih_d@Wout), fp16 hi/lo: (kt2, w4, nt4, lane64)
    for (int s = tid; s < 2*4*4*64; s += nthr) {
        const int lane = s & 63, nt = (s >> 6) & 3, w = (s >> 8) & 3, kt = s >> 10;
        const int rg = lane >> 4;
        const int n = nt*64 + w*16 + (lane & 15);
        const float sc = (nt == 2) ? S_TANH : S_SIG;
        short8 h0v, l0v, hcv, lcv;
        #pragma unroll
        for (int j = 0; j < 8; ++j) {
            const int k = kt*32 + rg*8 + j;
            const float w0 = Whh_d[n*64 + k];
            float a = w0;
            for (int d = 0; d < 32; ++d) a += Wih_d[n*D_IN + d] * Wout[d*64 + k];
            unsigned short h_, l_;
            split_f16(sc * w0, h_, l_); h0v[j] = (short)h_; l0v[j] = (short)l_;
            split_f16(sc * a,  h_, l_); hcv[j] = (short)h_; lcv[j] = (short)l_;
        }
        const size_t base = (size_t)(((((kt*4+w)*4+nt)*2+0)*64 + lane)) * 16;
        *(short8*)(ws + WS_DEC0 + base)         = h0v;
        *(short8*)(ws + WS_DEC0 + base + 64*16) = l0v;
        *(short8*)(ws + WS_COMB + base)         = hcv;
        *(short8*)(ws + WS_COMB + base + 64*16) = lcv;
    }

    // Wout fragments (fp16, hi used): (kt2, ot2, lane64); col = ot*16 + (lane&15)
    for (int s = tid; s < 2*2*64; s += nthr) {
        const int lane = s & 63, ot = (s >> 6) & 1, kt = s >> 7;
        const int rg = lane >> 4;
        const int ocol = ot*16 + (lane & 15);
        short8 hi8, lo8;
        #pragma unroll
        for (int j = 0; j < 8; ++j) {
            const int k = kt*32 + rg*8 + j;
            unsigned short h_, l_; split_f16(Wout[ocol*64 + k], h_, l_);
            hi8[j] = (short)h_; lo8[j] = (short)l_;
        }
        const size_t base = (size_t)((((kt*2+ot)*2+0)*64 + lane)) * 16;
        *(short8*)(ws + WS_OUT + base)         = hi8;
        *(short8*)(ws + WS_OUT + base + 64*16) = lo8;
    }

    // gate biases: (w4, nt4, lane64)
    for (int s = tid; s < 4*4*64; s += nthr) {
        const int lane = s & 63, nt = (s >> 6) & 3, w = s >> 8;
        const int n = nt*64 + w*16 + (lane & 15);
        const float sc = (nt == 2) ? S_TANH : S_SIG;
        float a = b_d[n];
        for (int d = 0; d < 32; ++d) a += Wih_d[n*D_IN + d] * bout[d];
        ((float*)(ws + WS_BENC))[s]  = sc * b_e[n];
        ((float*)(ws + WS_BDEC0))[s] = sc * b_d[n];
        ((float*)(ws + WS_BCOMB))[s] = sc * a;
    }
    for (int s = tid; s < 2*64; s += nthr)
        ((float*)(ws + WS_BOUT))[s] = bout[(s >> 6)*16 + (s & 15)];
}

// ==================== main kernel: 512 blocks x 4 waves x 8 rows ====================
extern "C" __global__ void __launch_bounds__(BDIM, 2)
seq2seq_main(const float* __restrict__ x, const char* __restrict__ ws,
             float* __restrict__ out)
{
    __shared__ __align__(16) char lds[LDS_BYTES];

    const int tid  = threadIdx.x;
    const int w    = tid >> 6;            // 0..3
    const int lane = tid & 63;
    const int rg   = lane >> 4;
    const int lcol = lane & 15;
    const int row0 = blockIdx.x * ROWS;

    // h position of this lane's unit = w*16 + lcol  (k = unit)
    const int KT_H = w >> 1;
    const int G_H  = ((w & 1) << 1) | (lcol >> 3);
    const int JH   = lcol & 7;

    // direct-x geometry: lane's A tile-row = lcol; real iff (lcol&3)<2; real row = 2*(lcol>>2)+(lcol&1)
    const bool xval = ((lcol & 3) < 2);
    const int  rrow = 2*(lcol >> 2) + (lcol & 1);
    const float* xbase = x + (size_t)(row0 + rrow) * T_SEQ * D_IN + rg*8;

    float c2[2] = {0.f, 0.f};

    // ---- encoder weights (fp16 hi/lo) + bias ----
    half8 whi[3][4], wlo[3][4];
    float bias[4];
    #pragma unroll
    for (int kt = 0; kt < 3; ++kt)
        #pragma unroll
        for (int nt = 0; nt < 4; ++nt) {
            const size_t base = (size_t)(((((kt*4+w)*4+nt)*2+0)*64 + lane)) * 16;
            whi[kt][nt] = *(const half8*)(ws + WS_ENC + base);
            wlo[kt][nt] = *(const half8*)(ws + WS_ENC + base + 64*16);
        }
    #pragma unroll
    for (int nt = 0; nt < 4; ++nt)
        bias[nt] = ((const float*)(ws + WS_BENC))[(w*4+nt)*64 + lane];

    // zero ALL LDS (padding rows must stay 0 forever)
    for (int i = tid; i < LDS_BYTES/4; i += BDIM) ((uint32_t*)lds)[i] = 0u;

    // x prefetch pipeline (2-step lead), per-wave direct loads
    float4_ cA = *(const float4_*)(xbase);
    float4_ cB = *(const float4_*)(xbase + 4);
    float4_ nA = *(const float4_*)(xbase + D_IN);
    float4_ nB = *(const float4_*)(xbase + D_IN + 4);
    lds_barrier();

    const half8 hz = {};
    auto mk_ax = [&](const float4_ &a, const float4_ &b) -> half8 {
        union { fp16x2 h2[4]; half8 h8; } u;
        u.h2[0] = __builtin_amdgcn_cvt_pkrtz(a[0], a[1]);
        u.h2[1] = __builtin_amdgcn_cvt_pkrtz(a[2], a[3]);
        u.h2[2] = __builtin_amdgcn_cvt_pkrtz(b[0], b[1]);
        u.h2[3] = __builtin_amdgcn_cvt_pkrtz(b[2], b[3]);
        return xval ? u.h8 : hz;
    };

    // ---------------- encoder: fp16 2-term, no-exchange, direct-x ----------------
    auto enc_mfma = [&](const half8 &ax, const half8 &ah0, const half8 &ah1,
                        float (&v0)[4], float (&v1)[4]) {
        __builtin_amdgcn_s_setprio(1);
        #pragma unroll
        for (int nt = 0; nt < 4; ++nt) {
            float4_ c = {bias[nt], bias[nt], bias[nt], bias[nt]};
            c = MFMAH(ax,  whi[0][nt], c);
            c = MFMAH(ah0, whi[1][nt], c);
            c = MFMAH(ah1, whi[2][nt], c);
            c = MFMAH(ax,  wlo[0][nt], c);
            c = MFMAH(ah0, wlo[1][nt], c);
            c = MFMAH(ah1, wlo[2][nt], c);
            v0[nt] = c[0]; v1[nt] = c[1];
        }
        __builtin_amdgcn_s_setprio(0);
    };

    auto enc_step = [&](int CUR, int t) {
        const int NXT = CUR ^ 1;
        const half8 ax = mk_ax(cA, cB);
        cA = nA; cB = nB;                       // rotate pipeline
        const int tn = (t + 2 < T_SEQ) ? (t + 2) : (T_SEQ - 1);
        nA = *(const float4_*)(xbase + (size_t)tn * D_IN);
        nB = *(const float4_*)(xbase + (size_t)tn * D_IN + 4);

        const half8 ah0 = *(const half8*)(lds + ENC_H(CUR, 0, rg) + lcol*16);
        const half8 ah1 = *(const half8*)(lds + ENC_H(CUR, 1, rg) + lcol*16);
        float v0[4], v1[4];
        enc_mfma(ax, ah0, ah1, v0, v1);

        const float h0 = lstm_h(v0[0], v0[1], v0[2], v0[3], c2[0]);
        const float h1 = lstm_h(v1[0], v1[1], v1[2], v1[3], c2[1]);
        const int rb = rg*64 + JH*2;            // tile rows rg*4, rg*4+1
        *(unsigned short*)(lds + ENC_H(NXT, KT_H, G_H) + rb)      = f16_bits(h0);
        *(unsigned short*)(lds + ENC_H(NXT, KT_H, G_H) + rb + 16) = f16_bits(h1);
        lds_barrier();
    };

    int t = 0;
    for (int it = 0; it < 249; ++it) { enc_step(0, t); ++t; enc_step(1, t); ++t; }
    enc_step(0, 498);
    {   // final encoder step t=499: read buf1, write fp16 h_enc into DEC buf0
        const half8 ax = mk_ax(cA, cB);
        const half8 ah0 = *(const half8*)(lds + ENC_H(1, 0, rg) + lcol*16);
        const half8 ah1 = *(const half8*)(lds + ENC_H(1, 1, rg) + lcol*16);
        float v0[4], v1[4];
        enc_mfma(ax, ah0, ah1, v0, v1);
        const float h0 = lstm_h(v0[0], v0[1], v0[2], v0[3], c2[0]);
        const float h1 = lstm_h(v1[0], v1[1], v1[2], v1[3], c2[1]);
        const int rb = rg*64 + JH*2;
        *(unsigned short*)(lds + DEC_H(0, KT_H, G_H) + rb)      = f16_bits(h0);
        *(unsigned short*)(lds + DEC_H(0, KT_H, G_H) + rb + 16) = f16_bits(h1);
        lds_barrier();
    }

    // ---------------- decoder: fp16 2-term, no-exchange ----------------
    half8 qhi[2][4], qlo[2][4];
    auto load_dec = [&](size_t wsoff, size_t boff) {
        #pragma unroll
        for (int kt = 0; kt < 2; ++kt)
            #pragma unroll
            for (int nt = 0; nt < 4; ++nt) {
                const size_t base = (size_t)(((((kt*4+w)*4+nt)*2+0)*64 + lane)) * 16;
                qhi[kt][nt] = *(const half8*)(ws + wsoff + base);
                qlo[kt][nt] = *(const half8*)(ws + wsoff + base + 64*16);
            }
        #pragma unroll
        for (int nt = 0; nt < 4; ++nt)
            bias[nt] = ((const float*)(ws + boff))[(w*4+nt)*64 + lane];
    };
    auto pw_dec = [&](const float (&v0)[4], const float (&v1)[4], int nxt) {
        const float h0 = lstm_h(v0[0], v0[1], v0[2], v0[3], c2[0]);
        const float h1 = lstm_h(v1[0], v1[1], v1[2], v1[3], c2[1]);
        const int rb = rg*64 + JH*2;
        *(unsigned short*)(lds + DEC_H(nxt, KT_H, G_H) + rb)      = f16_bits(h0);
        *(unsigned short*)(lds + DEC_H(nxt, KT_H, G_H) + rb + 16) = f16_bits(h1);
    };

    // out-wave setup: wave 0 -> cols 0..15, wave 2 -> cols 16..31 (different SIMDs)
    const bool ow  = (w == 0) || (w == 2);
    const int  tlo = w >> 1;
    const int  ocol = tlo*16 + lcol;
    half8 woh[2] = {};
    float bo = 0.f;
    if (ow) {
        #pragma unroll
        for (int kt = 0; kt < 2; ++kt)
            woh[kt] = *(const half8*)(ws + WS_OUT + (size_t)((((kt*2+tlo)*2+0)*64 + lane)) * 16);
        bo = ((const float*)(ws + WS_BOUT))[tlo*64 + lane];
    }

    // decoder step 0 (input zeros; Whh_d)
    load_dec(WS_DEC0, WS_BDEC0);
    {
        const half8 a0 = *(const half8*)(lds + DEC_H(0,0,rg) + lcol*16);
        const half8 a1 = *(const half8*)(lds + DEC_H(0,1,rg) + lcol*16);
        float v0[4], v1[4];
        __builtin_amdgcn_s_setprio(1);
        #pragma unroll
        for (int nt = 0; nt < 4; ++nt) {
            float4_ c = {bias[nt], bias[nt], bias[nt], bias[nt]};
            c = MFMAH(a0, qhi[0][nt], c);
            c = MFMAH(a1, qhi[1][nt], c);
            c = MFMAH(a0, qlo[0][nt], c);
            c = MFMAH(a1, qlo[1][nt], c);
            v0[nt] = c[0]; v1[nt] = c[1];
        }
        __builtin_amdgcn_s_setprio(0);
        pw_dec(v0, v1, 1);
        lds_barrier();
    }

    // decoder steps 1..499 (Wcomb; out hi-only side-store)
    load_dec(WS_COMB, WS_BCOMB);

    auto dec_step = [&](int CUR, int s) {
        const half8 a0 = *(const half8*)(lds + DEC_H(CUR,0,rg) + lcol*16);
        const half8 a1 = *(const half8*)(lds + DEC_H(CUR,1,rg) + lcol*16);
        float v0[4], v1[4];
        float4_ om = {bo, bo, bo, bo};
        __builtin_amdgcn_s_setprio(1);
        #pragma unroll
        for (int nt = 0; nt < 4; ++nt) {
            float4_ c = {bias[nt], bias[nt], bias[nt], bias[nt]};
            c = MFMAH(a0, qhi[0][nt], c);
            c = MFMAH(a1, qhi[1][nt], c);
            c = MFMAH(a0, qlo[0][nt], c);
            c = MFMAH(a1, qlo[1][nt], c);
            v0[nt] = c[0]; v1[nt] = c[1];
        }
        if (ow) {
            om = MFMAH(a0, woh[0], om);
            om = MFMAH(a1, woh[1], om);
        }
        __builtin_amdgcn_s_setprio(0);
        if (ow) {   // out_{s-1} = h_s @ Wout^T + bout (hi-only); stores fly across barrier
            out[((size_t)(row0 + 2*rg + 0)*T_SEQ + (s-1))*D_IN + ocol] = om[0];
            out[((size_t)(row0 + 2*rg + 1)*T_SEQ + (s-1))*D_IN + ocol] = om[1];
        }
        pw_dec(v0, v1, CUR ^ 1);
        lds_barrier();
    };

    int s = 1;
    for (int it = 0; it < 249; ++it) { dec_step(1, s); ++s; dec_step(0, s); ++s; }
    dec_step(1, 499);   // writes h_500 into DEC buf0

    // tail: out_499 = h_500 @ Wout^T + bout
    if (ow) {
        const half8 a0 = *(const half8*)(lds + DEC_H(0,0,rg) + lcol*16);
        const half8 a1 = *(const half8*)(lds + DEC_H(0,1,rg) + lcol*16);
        float4_ om = {bo, bo, bo, bo};
        om = MFMAH(a0, woh[0], om);
        om = MFMAH(a1, woh[1], om);
        out[((size_t)(row0 + 2*rg + 0)*T_SEQ + (T_SEQ-1))*D_IN + ocol] = om[0];
        out[((size_t)(row0 + 2*rg + 1)*T_SEQ + (T_SEQ-1))*D_IN + ocol] = om[1];
    }
}

extern "C" void kernel_launch(void* const* d_in, const int* in_sizes, int n_in,
                              void* d_out, int out_size, void* d_ws, size_t ws_size,
                              hipStream_t stream) {
    (void)n_in; (void)ws_size; (void)out_size;
    const float* x     = (const float*)d_in[0];
    const float* Wih_e = (const float*)d_in[1];
    const float* Whh_e = (const float*)d_in[2];
    const float* b_e   = (const float*)d_in[3];
    const float* Wih_d = (const float*)d_in[4];
    const float* Whh_d = (const float*)d_in[5];
    const float* b_d   = (const float*)d_in[6];
    const float* Wout  = (const float*)d_in[7];
    const float* bout  = (const float*)d_in[8];
    float* out = (float*)d_out;

    const int B = in_sizes[0] / (T_SEQ * D_IN);   // 4096

    hipLaunchKernelGGL(prep_kernel, dim3(8), dim3(512), 0, stream,
                       Wih_e, Whh_e, b_e, Wih_d, Whh_d, b_d, Wout, bout, (char*)d_ws);
    hipLaunchKernelGGL(seq2seq_main, dim3(B / ROWS), dim3(BDIM), 0, stream,
                       x, (const char*)d_ws, out);
}

// Round 12
// 369.806 us; speedup vs baseline: 1.5823x; 1.5823x over previous
//
#include <hip/hip_runtime.h>
#include <stdint.h>

#define T_SEQ 500
#define D_IN  32
#define BDIM  256
#define ROWS  8

using short8  = __attribute__((ext_vector_type(8))) short;     // 8 x 16-bit payload
using half8   = __attribute__((ext_vector_type(8))) _Float16;  // 8 fp16
using float4_ = __attribute__((ext_vector_type(4))) float;     // MFMA C/D frag

#define MFMAH(a,b,c) __builtin_amdgcn_mfma_f32_16x16x32_f16((a),(b),(c),0,0,0)

// ---------------- LDS: 272B frag blocks (16 rows x 16B + 16B pad) ----------------
#define BLK 272
#define ENC_H(buf,kt,g)  ((((buf)*2+(kt))*4+(g))*BLK)                   // blocks 0..15
#define ENC_X(slot,g)    (16*BLK + ((slot)*4+(g))*BLK)                  // blocks 16..23
#define DEC_H(buf,kt,g)  (24*BLK + ((((buf)*2+(kt))*4+(g))*BLK))        // blocks 24..39
#define LDS_BYTES (40*BLK)   // 10880 B

// ---------------- workspace (bytes) — identical to r9 (proven; lo planes unused) ----------------
#define WS_ENC   0                                // [kt3][w4][nt4][hl2][lane64] x16B (fp16)
#define WS_DEC0  (WS_ENC  + 3*4*4*2*64*16)        // 98304  (fp16 hi/lo)
#define WS_COMB  (WS_DEC0 + 2*4*4*2*64*16)        // 163840 (fp16 hi/lo)
#define WS_OUT   (WS_COMB + 2*4*4*2*64*16)        // 229376 : [kt2][ot2][hl2][lane64] (fp16)
#define WS_BENC  (WS_OUT  + 2*2*2*64*16)          // 237568 : [w4][nt4][lane64] f32
#define WS_BDEC0 (WS_BENC  + 4*4*64*4)            // 241664
#define WS_BCOMB (WS_BDEC0 + 4*4*64*4)            // 245760
#define WS_BOUT  (WS_BCOMB + 4*4*64*4)            // 249856 : [ot2][lane64] f32

// gate scale folded into weights: i,f,o -> -log2(e); g -> +2*log2(e)
#define S_SIG  (-1.4426950408889634f)
#define S_TANH ( 2.8853900817779268f)

__device__ __forceinline__ void split_f16(float v, unsigned short &hi, unsigned short &lo) {
    _Float16 h = (_Float16)v;
    _Float16 l = (_Float16)(v - (float)h);
    union { _Float16 f; unsigned short u; } a, b;
    a.f = h; b.f = l; hi = a.u; lo = b.u;
}
__device__ __forceinline__ unsigned short f16_bits(float v) {
    union { _Float16 f; unsigned short u; } t; t.f = (_Float16)v; return t.u;
}
// LDS-only barrier (no vmcnt drain: out-stores and x-prefetch loads stay in flight)
__device__ __forceinline__ void lds_barrier() {
    asm volatile("s_waitcnt lgkmcnt(0)\n\ts_barrier" ::: "memory");
}
// fused-rcp LSTM pointwise (ip,fp,op pre-scaled by -log2e; gp by +2log2e)
__device__ __forceinline__ float lstm_h(float ip, float fp, float gp, float op, float &cc) {
    const float ei = __builtin_amdgcn_exp2f(ip);
    const float ef = __builtin_amdgcn_exp2f(fp);
    const float eg = __builtin_amdgcn_exp2f(gp);
    const float eo = __builtin_amdgcn_exp2f(op);
    const float pig = (eg - 1.0f) * __builtin_amdgcn_rcpf((1.0f + ei) * (1.0f + eg));
    const float fa  = __builtin_amdgcn_rcpf(1.0f + ef);
    cc = __builtin_fmaf(fa, cc, pig);
    const float ec = __builtin_amdgcn_exp2f(cc * -2.8853900817779268f);
    return (1.0f - ec) * __builtin_amdgcn_rcpf((1.0f + eo) * (1.0f + ec));
}

// ==================== prep kernel (identical to r9, proven) ====================
// col map: wave w (0..3), tile nt = GATE, col c -> unit = w*16 + c, weight row n = nt*64 + unit
// frag element j of lane (rg=lane>>4): k = kt*32 + rg*8 + j
__global__ void __launch_bounds__(512)
prep_kernel(const float* __restrict__ Wih_e, const float* __restrict__ Whh_e,
            const float* __restrict__ b_e,
            const float* __restrict__ Wih_d, const float* __restrict__ Whh_d,
            const float* __restrict__ b_d,
            const float* __restrict__ Wout, const float* __restrict__ bout,
            char* __restrict__ ws)
{
    const int tid  = blockIdx.x * blockDim.x + threadIdx.x;
    const int nthr = gridDim.x * blockDim.x;

    // encoder fragments (fp16 hi/lo): slots (kt3, w4, nt4, lane64)
    for (int s = tid; s < 3*4*4*64; s += nthr) {
        const int lane = s & 63, nt = (s >> 6) & 3, w = (s >> 8) & 3, kt = s >> 10;
        const int rg = lane >> 4;
        const int n = nt*64 + w*16 + (lane & 15);
        const float sc = (nt == 2) ? S_TANH : S_SIG;
        short8 hi8, lo8;
        #pragma unroll
        for (int j = 0; j < 8; ++j) {
            const int k = kt*32 + rg*8 + j;
            const float wv = sc * ((k < 32) ? Wih_e[n*D_IN + k] : Whh_e[n*64 + k - 32]);
            unsigned short h_, l_; split_f16(wv, h_, l_);
            hi8[j] = (short)h_; lo8[j] = (short)l_;
        }
        const size_t base = (size_t)(((((kt*4+w)*4+nt)*2+0)*64 + lane)) * 16;
        *(short8*)(ws + WS_ENC + base)           = hi8;
        *(short8*)(ws + WS_ENC + base + 64*16)   = lo8;
    }

    // decoder step-0 (Whh_d) and combined (Whh_d + Wih_d@Wout), fp16 hi/lo: (kt2, w4, nt4, lane64)
    for (int s = tid; s < 2*4*4*64; s += nthr) {
        const int lane = s & 63, nt = (s >> 6) & 3, w = (s >> 8) & 3, kt = s >> 10;
        const int rg = lane >> 4;
        const int n = nt*64 + w*16 + (lane & 15);
        const float sc = (nt == 2) ? S_TANH : S_SIG;
        short8 h0v, l0v, hcv, lcv;
        #pragma unroll
        for (int j = 0; j < 8; ++j) {
            const int k = kt*32 + rg*8 + j;
            const float w0 = Whh_d[n*64 + k];
            float a = w0;
            for (int d = 0; d < 32; ++d) a += Wih_d[n*D_IN + d] * Wout[d*64 + k];
            unsigned short h_, l_;
            split_f16(sc * w0, h_, l_); h0v[j] = (short)h_; l0v[j] = (short)l_;
            split_f16(sc * a,  h_, l_); hcv[j] = (short)h_; lcv[j] = (short)l_;
        }
        const size_t base = (size_t)(((((kt*4+w)*4+nt)*2+0)*64 + lane)) * 16;
        *(short8*)(ws + WS_DEC0 + base)         = h0v;
        *(short8*)(ws + WS_DEC0 + base + 64*16) = l0v;
        *(short8*)(ws + WS_COMB + base)         = hcv;
        *(short8*)(ws + WS_COMB + base + 64*16) = lcv;
    }

    // Wout fragments (fp16, hi used): (kt2, ot2, lane64); col = ot*16 + (lane&15)
    for (int s = tid; s < 2*2*64; s += nthr) {
        const int lane = s & 63, ot = (s >> 6) & 1, kt = s >> 7;
        const int rg = lane >> 4;
        const int ocol = ot*16 + (lane & 15);
        short8 hi8, lo8;
        #pragma unroll
        for (int j = 0; j < 8; ++j) {
            const int k = kt*32 + rg*8 + j;
            unsigned short h_, l_; split_f16(Wout[ocol*64 + k], h_, l_);
            hi8[j] = (short)h_; lo8[j] = (short)l_;
        }
        const size_t base = (size_t)((((kt*2+ot)*2+0)*64 + lane)) * 16;
        *(short8*)(ws + WS_OUT + base)         = hi8;
        *(short8*)(ws + WS_OUT + base + 64*16) = lo8;
    }

    // gate biases: (w4, nt4, lane64)
    for (int s = tid; s < 4*4*64; s += nthr) {
        const int lane = s & 63, nt = (s >> 6) & 3, w = s >> 8;
        const int n = nt*64 + w*16 + (lane & 15);
        const float sc = (nt == 2) ? S_TANH : S_SIG;
        float a = b_d[n];
        for (int d = 0; d < 32; ++d) a += Wih_d[n*D_IN + d] * bout[d];
        ((float*)(ws + WS_BENC))[s]  = sc * b_e[n];
        ((float*)(ws + WS_BDEC0))[s] = sc * b_d[n];
        ((float*)(ws + WS_BCOMB))[s] = sc * a;
    }
    for (int s = tid; s < 2*64; s += nthr)
        ((float*)(ws + WS_BOUT))[s] = bout[(s >> 6)*16 + (s & 15)];
}

// ==================== main kernel: 512 blocks x 4 waves x 8 rows ====================
extern "C" __global__ void __launch_bounds__(BDIM, 2)
seq2seq_main(const float* __restrict__ x, const char* __restrict__ ws,
             float* __restrict__ out)
{
    __shared__ __align__(16) char lds[LDS_BYTES];

    const int tid  = threadIdx.x;
    const int w    = tid >> 6;            // 0..3
    const int lane = tid & 63;
    const int rg   = lane >> 4;
    const int lcol = lane & 15;
    const int row0 = blockIdx.x * ROWS;

    // h position of this lane's unit = w*16 + lcol  (k = unit)
    const int KT_H = w >> 1;
    const int G_H  = ((w & 1) << 1) | (lcol >> 3);
    const int JH   = lcol & 7;
    // x staging: batch row srow, k sk; tile row xtr (real rows at tile rows rg*4+{0,1})
    const int srow = tid >> 5, sk = tid & 31;
    const int xg = sk >> 3, xj = sk & 7;
    const int xtr = ((srow >> 1) << 2) | (srow & 1);

    float c2[2] = {0.f, 0.f};

    // ---- encoder weights (fp16 hi ONLY) + bias ----
    half8 whi[3][4];
    float bias[4];
    #pragma unroll
    for (int kt = 0; kt < 3; ++kt)
        #pragma unroll
        for (int nt = 0; nt < 4; ++nt) {
            const size_t base = (size_t)(((((kt*4+w)*4+nt)*2+0)*64 + lane)) * 16;
            whi[kt][nt] = *(const half8*)(ws + WS_ENC + base);
        }
    #pragma unroll
    for (int nt = 0; nt < 4; ++nt)
        bias[nt] = ((const float*)(ws + WS_BENC))[(w*4+nt)*64 + lane];

    // zero ALL LDS (padding rows must stay 0 forever)
    for (int i = tid; i < LDS_BYTES/4; i += BDIM) ((uint32_t*)lds)[i] = 0u;

    // stage x[0]; prefetch x[1], x[2]
    *(unsigned short*)(lds + ENC_X(0, xg) + xtr*16 + xj*2) =
        f16_bits(x[((size_t)(row0 + srow)*T_SEQ + 0)*D_IN + sk]);
    float xc = x[((size_t)(row0 + srow)*T_SEQ + 1)*D_IN + sk];
    float xn = x[((size_t)(row0 + srow)*T_SEQ + 2)*D_IN + sk];
    lds_barrier();

    // ---------------- encoder: fp16 hi-only, no-exchange ----------------
    auto enc_gemm = [&](int CUR, float (&v0)[4], float (&v1)[4]) {
        const half8 ax  = *(const half8*)(lds + ENC_X(CUR, rg) + lcol*16);
        const half8 ah0 = *(const half8*)(lds + ENC_H(CUR, 0, rg) + lcol*16);
        const half8 ah1 = *(const half8*)(lds + ENC_H(CUR, 1, rg) + lcol*16);
        #pragma unroll
        for (int nt = 0; nt < 4; ++nt) {
            float4_ c = {bias[nt], bias[nt], bias[nt], bias[nt]};
            c = MFMAH(ax,  whi[0][nt], c);
            c = MFMAH(ah0, whi[1][nt], c);
            c = MFMAH(ah1, whi[2][nt], c);
            v0[nt] = c[0];
            v1[nt] = c[1];
        }
    };

    auto enc_step = [&](int CUR, int t) {
        const int NXT = CUR ^ 1;
        float v0[4], v1[4];
        enc_gemm(CUR, v0, v1);
        const float xold = xc; xc = xn;
        const int tn = (t + 3 < T_SEQ) ? (t + 3) : (T_SEQ - 1);
        xn = x[((size_t)(row0 + srow)*T_SEQ + tn)*D_IN + sk];
        if (t + 1 < T_SEQ)
            *(unsigned short*)(lds + ENC_X(NXT, xg) + xtr*16 + xj*2) = f16_bits(xold);
        const float h0 = lstm_h(v0[0], v0[1], v0[2], v0[3], c2[0]);
        const float h1 = lstm_h(v1[0], v1[1], v1[2], v1[3], c2[1]);
        const int rb = rg*64 + JH*2;   // tile rows rg*4, rg*4+1
        *(unsigned short*)(lds + ENC_H(NXT, KT_H, G_H) + rb)      = f16_bits(h0);
        *(unsigned short*)(lds + ENC_H(NXT, KT_H, G_H) + rb + 16) = f16_bits(h1);
        lds_barrier();
    };

    int t = 0;
    for (int it = 0; it < 249; ++it) { enc_step(0, t); ++t; enc_step(1, t); ++t; }
    enc_step(0, 498);
    {   // final encoder step t=499: read buf1, write fp16 h_enc into DEC buf0
        float v0[4], v1[4];
        enc_gemm(1, v0, v1);
        const float h0 = lstm_h(v0[0], v0[1], v0[2], v0[3], c2[0]);
        const float h1 = lstm_h(v1[0], v1[1], v1[2], v1[3], c2[1]);
        const int rb = rg*64 + JH*2;
        *(unsigned short*)(lds + DEC_H(0, KT_H, G_H) + rb)      = f16_bits(h0);
        *(unsigned short*)(lds + DEC_H(0, KT_H, G_H) + rb + 16) = f16_bits(h1);
        lds_barrier();
    }

    // ---------------- decoder: fp16 hi-only, no-exchange ----------------
    half8 qhi[2][4];
    auto load_dec = [&](size_t wsoff, size_t boff) {
        #pragma unroll
        for (int kt = 0; kt < 2; ++kt)
            #pragma unroll
            for (int nt = 0; nt < 4; ++nt) {
                const size_t base = (size_t)(((((kt*4+w)*4+nt)*2+0)*64 + lane)) * 16;
                qhi[kt][nt] = *(const half8*)(ws + wsoff + base);
            }
        #pragma unroll
        for (int nt = 0; nt < 4; ++nt)
            bias[nt] = ((const float*)(ws + boff))[(w*4+nt)*64 + lane];
    };
    auto pw_dec = [&](const float (&v0)[4], const float (&v1)[4], int nxt) {
        const float h0 = lstm_h(v0[0], v0[1], v0[2], v0[3], c2[0]);
        const float h1 = lstm_h(v1[0], v1[1], v1[2], v1[3], c2[1]);
        const int rb = rg*64 + JH*2;
        *(unsigned short*)(lds + DEC_H(nxt, KT_H, G_H) + rb)      = f16_bits(h0);
        *(unsigned short*)(lds + DEC_H(nxt, KT_H, G_H) + rb + 16) = f16_bits(h1);
    };

    // out-wave setup: wave 0 -> cols 0..15, wave 2 -> cols 16..31 (different SIMDs)
    const bool ow  = (w == 0) || (w == 2);
    const int  tlo = w >> 1;
    const int  ocol = tlo*16 + lcol;
    half8 woh[2] = {};
    float bo = 0.f;
    if (ow) {
        #pragma unroll
        for (int kt = 0; kt < 2; ++kt)
            woh[kt] = *(const half8*)(ws + WS_OUT + (size_t)((((kt*2+tlo)*2+0)*64 + lane)) * 16);
        bo = ((const float*)(ws + WS_BOUT))[tlo*64 + lane];
    }

    // decoder step 0 (input zeros; Whh_d)
    load_dec(WS_DEC0, WS_BDEC0);
    {
        const half8 a0 = *(const half8*)(lds + DEC_H(0,0,rg) + lcol*16);
        const half8 a1 = *(const half8*)(lds + DEC_H(0,1,rg) + lcol*16);
        float v0[4], v1[4];
        #pragma unroll
        for (int nt = 0; nt < 4; ++nt) {
            float4_ c = {bias[nt], bias[nt], bias[nt], bias[nt]};
            c = MFMAH(a0, qhi[0][nt], c);
            c = MFMAH(a1, qhi[1][nt], c);
            v0[nt] = c[0];
            v1[nt] = c[1];
        }
        pw_dec(v0, v1, 1);
        lds_barrier();
    }

    // decoder steps 1..499 (Wcomb; out hi-only side-store)
    load_dec(WS_COMB, WS_BCOMB);

    auto dec_step = [&](int CUR, int s) {
        const half8 a0 = *(const half8*)(lds + DEC_H(CUR,0,rg) + lcol*16);
        const half8 a1 = *(const half8*)(lds + DEC_H(CUR,1,rg) + lcol*16);
        float v0[4], v1[4];
        #pragma unroll
        for (int nt = 0; nt < 4; ++nt) {
            float4_ c = {bias[nt], bias[nt], bias[nt], bias[nt]};
            c = MFMAH(a0, qhi[0][nt], c);
            c = MFMAH(a1, qhi[1][nt], c);
            v0[nt] = c[0];
            v1[nt] = c[1];
        }
        if (ow) {   // out_{s-1} = h_s @ Wout^T + bout (hi-only); stores fly across barrier
            float4_ om = {bo, bo, bo, bo};
            om = MFMAH(a0, woh[0], om);
            om = MFMAH(a1, woh[1], om);
            out[((size_t)(row0 + 2*rg + 0)*T_SEQ + (s-1))*D_IN + ocol] = om[0];
            out[((size_t)(row0 + 2*rg + 1)*T_SEQ + (s-1))*D_IN + ocol] = om[1];
        }
        pw_dec(v0, v1, CUR ^ 1);
        lds_barrier();
    };

    int s = 1;
    for (int it = 0; it < 249; ++it) { dec_step(1, s); ++s; dec_step(0, s); ++s; }
    dec_step(1, 499);   // writes h_500 into DEC buf0

    // tail: out_499 = h_500 @ Wout^T + bout
    if (ow) {
        const half8 a0 = *(const half8*)(lds + DEC_H(0,0,rg) + lcol*16);
        const half8 a1 = *(const half8*)(lds + DEC_H(0,1,rg) + lcol*16);
        float4_ om = {bo, bo, bo, bo};
        om = MFMAH(a0, woh[0], om);
        om = MFMAH(a1, woh[1], om);
        out[((size_t)(row0 + 2*rg + 0)*T_SEQ + (T_SEQ-1))*D_IN + ocol] = om[0];
        out[((size_t)(row0 + 2*rg + 1)*T_SEQ + (T_SEQ-1))*D_IN + ocol] = om[1];
    }
}

extern "C" void kernel_launch(void* const* d_in, const int* in_sizes, int n_in,
                              void* d_out, int out_size, void* d_ws, size_t ws_size,
                              hipStream_t stream) {
    (void)n_in; (void)ws_size; (void)out_size;
    const float* x     = (const float*)d_in[0];
    const float* Wih_e = (const float*)d_in[1];
    const float* Whh_e = (const float*)d_in[2];
    const float* b_e   = (const float*)d_in[3];
    const float* Wih_d = (const float*)d_in[4];
    const float* Whh_d = (const float*)d_in[5];
    const float* b_d   = (const float*)d_in[6];
    const float* Wout  = (const float*)d_in[7];
    const float* bout  = (const float*)d_in[8];
    float* out = (float*)d_out;

    const int B = in_sizes[0] / (T_SEQ * D_IN);   // 4096

    hipLaunchKernelGGL(prep_kernel, dim3(8), dim3(512), 0, stream,
                       Wih_e, Whh_e, b_e, Wih_d, Whh_d, b_d, Wout, bout, (char*)d_ws);
    hipLaunchKernelGGL(seq2seq_main, dim3(B / ROWS), dim3(BDIM), 0, stream,
                       x, (const char*)d_ws, out);
}